// Round 7
// baseline (1065.032 us; speedup 1.0000x reference)
//
#include <hip/hip_runtime.h>
#include <hip/hip_cooperative_groups.h>

namespace cg = cooperative_groups;

typedef __attribute__((ext_vector_type(8))) short short8;
typedef __attribute__((ext_vector_type(4))) float f32x4;
typedef __attribute__((ext_vector_type(2))) float f32x2;
typedef __attribute__((ext_vector_type(4))) unsigned int uint4v;
typedef unsigned short u16;

#define NI 2048   // input capsules
// B=64, J=32, D=16, E=16, JD=512. Inputs fp32; compute bf16 MFMA.

// bf16 RNE pack of two floats -> dword (lo=a, hi=b)
__device__ __forceinline__ unsigned int packbf2(float a, float b){
  unsigned int ua = __float_as_uint(a), ub = __float_as_uint(b);
  unsigned int ra = (ua + 0x7FFFu + ((ua >> 16) & 1u)) >> 16;
  unsigned int rb = (ub + 0x7FFFu + ((ub >> 16) & 1u)) & 0xFFFF0000u;
  return ra | rb;
}
__device__ __forceinline__ float bflo(unsigned int p){ return __uint_as_float(p << 16); }
__device__ __forceinline__ float bfhi(unsigned int p){ return __uint_as_float(p & 0xFFFF0000u); }

__device__ __forceinline__ uint4v cvt8(const f32x4& a, const f32x4& b){
  uint4v p = { packbf2(a.x, a.y), packbf2(a.z, a.w),
               packbf2(b.x, b.y), packbf2(b.z, b.w) };
  return p;
}

// async global->LDS, 16 B per lane; lds dest = wave-uniform base (+ implicit lane*16)
__device__ __forceinline__ void gl_lds16(const void* g, void* l){
  __builtin_amdgcn_global_load_lds(
      (const __attribute__((address_space(1))) unsigned int*)g,
      (__attribute__((address_space(3))) unsigned int*)l, 16, 0, 0);
}

// ======================= fused cooperative kernel =======================
// Grid MUST be 512 blocks x 256 threads (2 blocks/CU co-resident: 36 KB LDS,
// <=256 VGPR). Phases separated by grid.sync():
//  P: convert W->bf16, X->bf16 transposed [i][b][e]   (work split by bhalf)
//  A: uniform-c accumulate  -> partials
//  R: all-block coalesced reduce -> S_buf  (scale per phase)
//  V: per-thread redundant squash_J from L2-hot S_buf -> v packs (no sync)
//  B/C: softmax passes (register softmax, u kept in regs) -> partials
//  final: squash_D by blocks 0..63 -> out
__global__ __launch_bounds__(256, 2)
void caps_fused(const float* __restrict__ W, const float* __restrict__ X,
                u16* __restrict__ Wb, u16* __restrict__ Xb,
                float* __restrict__ partials, float* __restrict__ S_buf,
                float* __restrict__ out)
{
  cg::grid_group grid = cg::this_grid();
  __shared__ __align__(16) u16 sW[2][8192];
  __shared__ __align__(16) u16 sX[2][512];
  __shared__ float sSum[4][16];
  __shared__ float sRed[4][64];
  __shared__ float ssq[32];

  const int t     = threadIdx.x;
  const int w     = t >> 6;
  const int lane  = t & 63;
  const int wtile = w & 1;
  const int jhalf = w >> 1;
  const int lq    = lane >> 4;
  const int lb    = lane & 15;
  const int q1    = lq & 1;
  const int bhalf = blockIdx.x & 1;
  const int iblk  = blockIdx.x >> 1;
  const int bloc  = wtile * 16 + lb;
  const int bg    = bhalf * 32 + bloc;
  const int i0    = iblk * 8;                  // CI = 8 rows per block

  const short8 zero8 = {0,0,0,0,0,0,0,0};
  const f32x4  zf4   = {0.f,0.f,0.f,0.f};

  // ---------- phase P: dtype conversion (balanced across bhalf) ----------
  {
    // each block converts 4 W rows: i0 + bhalf*4 .. +4
    #pragma unroll
    for (int r = 0; r < 4; ++r){
      const int row = i0 + bhalf * 4 + r;
      const float* src = W + (size_t)row * 8192;
      u16* dst = Wb + (size_t)row * 8192;
      #pragma unroll
      for (int cc = 0; cc < 4; ++cc){
        int c = cc * 256 + t;
        f32x4 a = *(const f32x4*)(src + c * 8);
        f32x4 b = *(const f32x4*)(src + c * 8 + 4);
        *(uint4v*)(dst + c * 8) = cvt8(a, b);
      }
    }
    // each block converts 256 (i,b) X pairs (transpose to [i][b][e])
    int p  = bhalf * 256 + t;                  // 0..511 within this iblk
    int ii = i0 + (p >> 6), b = p & 63;
    const float* src = X + ((size_t)b * NI + ii) * 16;
    f32x4 a0 = *(const f32x4*)(src);
    f32x4 a1 = *(const f32x4*)(src + 4);
    f32x4 a2 = *(const f32x4*)(src + 8);
    f32x4 a3 = *(const f32x4*)(src + 12);
    u16* dst = Xb + ((size_t)ii * 64 + b) * 16;
    *(uint4v*)(dst)     = cvt8(a0, a1);
    *(uint4v*)(dst + 8) = cvt8(a2, a3);
  }
  __threadfence();
  grid.sync();

  // ---------- shared helpers ----------
  f32x4 acc[16];
  auto zero_acc = [&]{
    #pragma unroll
    for (int tj = 0; tj < 16; ++tj) acc[tj] = zf4;
  };
  auto stage = [&](int nb, int irow){
    const u16* src = Wb + (size_t)irow * 8192 + (size_t)(w * 4) * 512;
    u16* dst = &sW[nb][w * 4 * 512];
    #pragma unroll
    for (int r = 0; r < 4; ++r)
      gl_lds16(src + r * 512 + lane * 8, dst + r * 512);
    if (w == 3)
      gl_lds16(Xb + ((size_t)irow * 64 + bhalf * 32) * 16 + lane * 8, &sX[nb][0]);
  };
  auto write_partials = [&]{
    float* dst = partials + ((size_t)blockIdx.x * 4 + (size_t)w) * 4096 + (size_t)lane * 64;
    #pragma unroll
    for (int tj = 0; tj < 16; ++tj) *(f32x4*)(dst + tj * 4) = acc[tj];
    __threadfence();
  };
  // all-block coalesced reduce of 256 planes -> S_buf (ends with grid.sync)
  auto reduce_phase = [&](float scale){
    const int T = blockIdx.x * 64 + lane;      // 64 T per block, 4 waves split planes
    const float* base = partials + (size_t)(w * 64) * 32768 + T;
    float v0 = 0.f, v1 = 0.f, v2 = 0.f, v3 = 0.f;
    #pragma unroll 4
    for (int bl = 0; bl < 64; bl += 4){
      v0 += base[(size_t)(bl + 0) * 32768];
      v1 += base[(size_t)(bl + 1) * 32768];
      v2 += base[(size_t)(bl + 2) * 32768];
      v3 += base[(size_t)(bl + 3) * 32768];
    }
    sRed[w][lane] = (v0 + v1) + (v2 + v3);
    __syncthreads();
    if (t < 64){
      float s = ((sRed[0][t] + sRed[1][t]) + (sRed[2][t] + sRed[3][t])) * scale;
      const int T2 = blockIdx.x * 64 + t;
      const int bh = T2 >> 14, ww = (T2 >> 12) & 3, l = (T2 >> 6) & 63, k = T2 & 63;
      const int b  = bh * 32 + (ww & 1) * 16 + (l & 15);
      const int jd = ((ww >> 1) * 16 + (k >> 2)) * 16 + ((l >> 4) << 2) + (k & 3);
      S_buf[b * 512 + jd] = s;
    }
    __threadfence();
    grid.sync();
  };
  // per-thread redundant squash_J from S_buf (L2-hot); result -> v packs
  unsigned int vpl[16], vph[16];
  auto vcomp = [&](bool addprev){
    const float* Srow = S_buf + bg * 512 + lq * 4;
    f32x4 sqv = zf4;
    #pragma unroll 8
    for (int j = 0; j < 32; ++j){
      f32x4 sv = *(const f32x4*)(Srow + j * 16);
      sqv.x += sv.x * sv.x; sqv.y += sv.y * sv.y;
      sqv.z += sv.z * sv.z; sqv.w += sv.w * sv.w;
    }
    f32x4 f;
    f.x = sqv.x / ((1.f + sqv.x) * sqrtf(sqv.x + 1e-8f));
    f.y = sqv.y / ((1.f + sqv.y) * sqrtf(sqv.y + 1e-8f));
    f.z = sqv.z / ((1.f + sqv.z) * sqrtf(sqv.z + 1e-8f));
    f.w = sqv.w / ((1.f + sqv.w) * sqrtf(sqv.w + 1e-8f));
    #pragma unroll
    for (int tj = 0; tj < 16; ++tj){
      f32x4 sv = *(const f32x4*)(Srow + (jhalf * 16 + tj) * 16);
      float vx = sv.x * f.x, vy = sv.y * f.y, vz = sv.z * f.z, vw = sv.w * f.w;
      if (addprev){
        vx += bflo(vpl[tj]); vy += bfhi(vpl[tj]);
        vz += bflo(vph[tj]); vw += bfhi(vph[tj]);
      }
      vpl[tj] = packbf2(vx, vy);
      vph[tj] = packbf2(vz, vw);
    }
  };
  // MODE-1 pass over this block's 8 rows (register softmax, u in regs)
  auto mode1_phase = [&]{
    zero_acc();
    stage(0, i0);
    __syncthreads();
    for (int s = 0; s < 8; ++s){
      const int buf = s & 1;
      if (s + 1 < 8) stage(buf ^ 1, i0 + s + 1);
      short8 bl8 = *(const short8*)(&sX[buf][bloc * 16 + q1 * 8]);
      short8 bfrag = (lq < 2) ? bl8 : zero8;       // K upper half zero
      f32x4 ut[16];
      float e[16];
      #pragma unroll
      for (int tj = 0; tj < 16; ++tj){
        int j = jhalf * 16 + tj;
        short8 al8 = *(const short8*)(&sW[buf][j * 256 + lb * 16 + q1 * 8]);
        short8 afrag = (lq < 2) ? al8 : zero8;
        ut[tj] = __builtin_amdgcn_mfma_f32_16x16x32_bf16(afrag, bfrag, zf4, 0, 0, 0);
        float p = ut[tj].x * bflo(vpl[tj]) + ut[tj].y * bfhi(vpl[tj])
                + ut[tj].z * bflo(vph[tj]) + ut[tj].w * bfhi(vph[tj]);
        p += __shfl_xor(p, 16, 64);
        p += __shfl_xor(p, 32, 64);    // every lane: full logit[j][its b]
        e[tj] = __expf(p);             // |logit| small -> fp32-safe w/o max-sub
      }
      float s01 = e[0] + e[1],   s23 = e[2] + e[3];
      float s45 = e[4] + e[5],   s67 = e[6] + e[7];
      float s89 = e[8] + e[9],   sab = e[10] + e[11];
      float scd = e[12] + e[13], sef = e[14] + e[15];
      float ps = ((s01 + s23) + (s45 + s67)) + ((s89 + sab) + (scd + sef));
      if (lane < 16) sSum[w][lane] = ps;
      __syncthreads();
      float inv = 1.0f / (ps + sSum[w ^ 2][lb]);
      #pragma unroll
      for (int tj = 0; tj < 16; ++tj){
        float c = e[tj] * inv;
        acc[tj].x += c * ut[tj].x;
        acc[tj].y += c * ut[tj].y;
        acc[tj].z += c * ut[tj].z;
        acc[tj].w += c * ut[tj].w;
      }
      __syncthreads();
    }
    write_partials();
    grid.sync();
  };

  // ---------- phase A: uniform c ----------
  zero_acc();
  stage(0, i0);
  __syncthreads();
  for (int s = 0; s < 8; ++s){
    const int buf = s & 1;
    if (s + 1 < 8) stage(buf ^ 1, i0 + s + 1);
    short8 bl8 = *(const short8*)(&sX[buf][bloc * 16 + q1 * 8]);
    short8 bfrag = (lq < 2) ? bl8 : zero8;
    #pragma unroll
    for (int tj = 0; tj < 16; ++tj){
      int j = jhalf * 16 + tj;
      short8 al8 = *(const short8*)(&sW[buf][j * 256 + lb * 16 + q1 * 8]);
      short8 afrag = (lq < 2) ? al8 : zero8;
      acc[tj] = __builtin_amdgcn_mfma_f32_16x16x32_bf16(afrag, bfrag, acc[tj], 0, 0, 0);
    }
    __syncthreads();
  }
  write_partials();
  grid.sync();

  reduce_phase(1.0f / 32.0f);   // S1
  vcomp(false);                 // v1
  mode1_phase();                // B
  reduce_phase(1.0f);           // S2
  vcomp(true);                  // v12 = v1 + squash(S2)  (in-place)
  mode1_phase();                // C
  reduce_phase(1.0f);           // S3

  // ---------- final: squash over D by blocks 0..63 ----------
  if (blockIdx.x < 64){
    const int b = blockIdx.x;
    if (t < 32) ssq[t] = 0.f;
    __syncthreads();
    float s0 = S_buf[b * 512 + t], s1 = S_buf[b * 512 + 256 + t];
    atomicAdd(&ssq[t >> 4], s0 * s0);
    atomicAdd(&ssq[(t + 256) >> 4], s1 * s1);
    __syncthreads();
    float q0 = ssq[t >> 4], q1 = ssq[(t + 256) >> 4];
    out[b * 512 + t]       = s0 * q0 / ((1.f + q0) * sqrtf(q0 + 1e-8f));
    out[b * 512 + 256 + t] = s1 * q1 / ((1.f + q1) * sqrtf(q1 + 1e-8f));
  }
}

// ======================= round-5 multi-kernel fallback =======================
__global__ __launch_bounds__(256)
void caps_prep(const float* __restrict__ W, const float* __restrict__ X,
               u16* __restrict__ Wb, u16* __restrict__ Xb)
{
  const int bid = blockIdx.x;
  if (bid < 8192){
    size_t base = (size_t)bid * 2048 + (size_t)threadIdx.x * 8;
    f32x4 a = *(const f32x4*)(W + base);
    f32x4 b = *(const f32x4*)(W + base + 4);
    *(uint4v*)(Wb + base) = cvt8(a, b);
  } else {
    int p = (bid - 8192) * 256 + threadIdx.x;
    int i = p >> 6, b = p & 63;
    const float* src = X + ((size_t)b * NI + i) * 16;
    f32x4 a0 = *(const f32x4*)(src);
    f32x4 a1 = *(const f32x4*)(src + 4);
    f32x4 a2 = *(const f32x4*)(src + 8);
    f32x4 a3 = *(const f32x4*)(src + 12);
    *(uint4v*)(Xb + (size_t)p * 16)     = cvt8(a0, a1);
    *(uint4v*)(Xb + (size_t)p * 16 + 8) = cvt8(a2, a3);
  }
}

template<int MODE>
__global__ __launch_bounds__(256, 2)
void caps_pass_mk(const u16* __restrict__ Wb, const u16* __restrict__ Xb,
                  const float* __restrict__ vbuf, float* __restrict__ partials, int CI)
{
  constexpr int WR = (MODE == 0) ? 2 : 1;
  __shared__ __align__(16) u16 sW[2][WR * 8192];
  __shared__ __align__(16) u16 sX[2][WR * 512];
  __shared__ float sSum[4][16];

  const int t = threadIdx.x, w = t >> 6, lane = t & 63;
  const int wtile = w & 1, jhalf = w >> 1, lq = lane >> 4, lb = lane & 15, q1 = lq & 1;
  const int bhalf = blockIdx.x & 1, iblk = blockIdx.x >> 1;
  const int bloc = wtile * 16 + lb, bg = bhalf * 32 + bloc;
  const size_t i0 = (size_t)iblk * (size_t)CI;
  const short8 zero8 = {0,0,0,0,0,0,0,0};
  const f32x4 zf4 = {0.f,0.f,0.f,0.f};

  f32x4 acc[16];
  #pragma unroll
  for (int tj = 0; tj < 16; ++tj) acc[tj] = zf4;

  unsigned int vpl[16], vph[16];
  if constexpr (MODE == 1){
    #pragma unroll
    for (int tj = 0; tj < 16; ++tj){
      f32x4 v = *(const f32x4*)(&vbuf[bg * 512 + (jhalf * 16 + tj) * 16 + lq * 4]);
      vpl[tj] = packbf2(v.x, v.y);
      vph[tj] = packbf2(v.z, v.w);
    }
  }

  auto stage = [&](int nb, size_t irow){
    #pragma unroll
    for (int rr = 0; rr < WR; ++rr){
      const u16* src = Wb + (irow + rr) * 8192 + (size_t)(w * 4) * 512;
      u16* dst = &sW[nb][rr * 8192 + w * 4 * 512];
      #pragma unroll
      for (int r = 0; r < 4; ++r)
        gl_lds16(src + r * 512 + lane * 8, dst + r * 512);
    }
    if (w >= 4 - WR){
      int rr = w - (4 - WR);
      gl_lds16(Xb + ((irow + rr) * 64 + (size_t)bhalf * 32) * 16 + lane * 8,
               &sX[nb][rr * 512]);
    }
  };

  const int NSTEP = CI / WR;
  stage(0, i0);
  __syncthreads();

  for (int s = 0; s < NSTEP; ++s){
    const int buf = s & 1;
    if (s + 1 < NSTEP) stage(buf ^ 1, i0 + (size_t)(s + 1) * WR);

    if constexpr (MODE == 0){
      const int rsel = lq >> 1;
      short8 bfrag = *(const short8*)(&sX[buf][rsel * 512 + bloc * 16 + q1 * 8]);
      #pragma unroll
      for (int tj = 0; tj < 16; ++tj){
        int j = jhalf * 16 + tj;
        short8 afrag = *(const short8*)(&sW[buf][rsel * 8192 + j * 256 + lb * 16 + q1 * 8]);
        acc[tj] = __builtin_amdgcn_mfma_f32_16x16x32_bf16(afrag, bfrag, acc[tj], 0, 0, 0);
      }
    } else {
      short8 bl8 = *(const short8*)(&sX[buf][bloc * 16 + q1 * 8]);
      short8 bfrag = (lq < 2) ? bl8 : zero8;
      f32x4 ut[16];
      float e[16];
      float ps = 0.f;
      #pragma unroll
      for (int tj = 0; tj < 16; ++tj){
        int j = jhalf * 16 + tj;
        short8 al8 = *(const short8*)(&sW[buf][j * 256 + lb * 16 + q1 * 8]);
        short8 afrag = (lq < 2) ? al8 : zero8;
        ut[tj] = __builtin_amdgcn_mfma_f32_16x16x32_bf16(afrag, bfrag, zf4, 0, 0, 0);
        float p = ut[tj].x * bflo(vpl[tj]) + ut[tj].y * bfhi(vpl[tj])
                + ut[tj].z * bflo(vph[tj]) + ut[tj].w * bfhi(vph[tj]);
        p += __shfl_xor(p, 16, 64);
        p += __shfl_xor(p, 32, 64);
        e[tj] = __expf(p);
        ps += e[tj];
      }
      if (lane < 16) sSum[w][lane] = ps;
      __syncthreads();
      float inv = 1.0f / (ps + sSum[w ^ 2][lb]);
      #pragma unroll
      for (int tj = 0; tj < 16; ++tj){
        float c = e[tj] * inv;
        acc[tj].x += c * ut[tj].x;
        acc[tj].y += c * ut[tj].y;
        acc[tj].z += c * ut[tj].z;
        acc[tj].w += c * ut[tj].w;
      }
    }
    __syncthreads();
  }

  float* dst = partials + ((size_t)blockIdx.x * 4 + (size_t)w) * 4096 + (size_t)lane * 64;
  #pragma unroll
  for (int tj = 0; tj < 16; ++tj) *(f32x4*)(dst + tj * 4) = acc[tj];
}

template<int MODE>
__global__ __launch_bounds__(256)
void caps_pass_legacy(const float* __restrict__ Wg, const float* __restrict__ Xg,
                      const float* __restrict__ vbuf, float* __restrict__ partials, int CI)
{
  __shared__ __align__(16) unsigned short sW[2][8192];
  __shared__ __align__(16) unsigned int   sXd[2][256];
  __shared__ float sLog[(MODE == 1) ? (32 * 33) : 4];
  const int t = threadIdx.x, w = t >> 6, lane = t & 63;
  const int wtile = w & 1, jhalf = w >> 1, lq = lane >> 4, lb = lane & 15, q1 = lq & 1;
  const int bhalf = blockIdx.x & 1, iblk = blockIdx.x >> 1;
  const int bloc = wtile * 16 + lb, bg = bhalf * 32 + bloc;
  const size_t i0 = (size_t)iblk * (size_t)CI;
  const short8 zero8 = {0,0,0,0,0,0,0,0};
  const f32x4 zf4 = {0.f,0.f,0.f,0.f};
  f32x4 acc[16];
  #pragma unroll
  for (int tj = 0; tj < 16; ++tj) acc[tj] = zf4;
  unsigned int vpl[16], vph[16];
  if constexpr (MODE == 1){
    #pragma unroll
    for (int tj = 0; tj < 16; ++tj){
      f32x4 v = *(const f32x4*)(&vbuf[bg * 512 + (jhalf * 16 + tj) * 16 + lq * 4]);
      vpl[tj] = packbf2(v.x, v.y); vph[tj] = packbf2(v.z, v.w);
    }
  }
  {
    const float* wsrc = Wg + i0 * 8192;
    #pragma unroll
    for (int r = 0; r < 4; ++r){
      int c = r * 256 + t;
      f32x4 a = *(const f32x4*)(&wsrc[c * 8]);
      f32x4 b = *(const f32x4*)(&wsrc[c * 8 + 4]);
      *(uint4v*)(&sW[0][c * 8]) = cvt8(a, b);
    }
    int bidx = bhalf * 32 + (t >> 3), e2 = t & 7;
    f32x2 xv = *(const f32x2*)(&Xg[((size_t)bidx * NI + i0) * 16 + e2 * 2]);
    sXd[0][t] = packbf2(xv.x, xv.y);
  }
  __syncthreads();
  for (int s = 0; s < CI; ++s){
    const int buf = s & 1;
    f32x4 wpa[4], wpb[4]; f32x2 xp;
    const bool more = (s + 1 < CI);
    if (more){
      const float* wsrc = Wg + (i0 + (size_t)(s + 1)) * 8192;
      #pragma unroll
      for (int r = 0; r < 4; ++r){
        int c = r * 256 + t;
        wpa[r] = *(const f32x4*)(&wsrc[c * 8]);
        wpb[r] = *(const f32x4*)(&wsrc[c * 8 + 4]);
      }
      int bidx = bhalf * 32 + (t >> 3), e2 = t & 7;
      xp = *(const f32x2*)(&Xg[((size_t)bidx * NI + i0 + s + 1) * 16 + e2 * 2]);
    }
    const unsigned short* xrow = (const unsigned short*)&sXd[buf][0];
    short8 bl8 = *(const short8*)(&xrow[bloc * 16 + q1 * 8]);
    short8 bfrag = (lq < 2) ? bl8 : zero8;
    if constexpr (MODE == 0){
      #pragma unroll
      for (int tj = 0; tj < 16; ++tj){
        int j = jhalf * 16 + tj;
        short8 al8 = *(const short8*)(&sW[buf][j * 256 + lb * 16 + q1 * 8]);
        short8 afrag = (lq < 2) ? al8 : zero8;
        acc[tj] = __builtin_amdgcn_mfma_f32_16x16x32_bf16(afrag, bfrag, acc[tj], 0, 0, 0);
      }
    } else {
      #pragma unroll
      for (int tj = 0; tj < 16; ++tj){
        int j = jhalf * 16 + tj;
        short8 al8 = *(const short8*)(&sW[buf][j * 256 + lb * 16 + q1 * 8]);
        short8 afrag = (lq < 2) ? al8 : zero8;
        f32x4 u = __builtin_amdgcn_mfma_f32_16x16x32_bf16(afrag, bfrag, zf4, 0, 0, 0);
        float p = u.x * bflo(vpl[tj]) + u.y * bfhi(vpl[tj])
                + u.z * bflo(vph[tj]) + u.w * bfhi(vph[tj]);
        p += __shfl_xor(p, 16, 64);
        p += __shfl_xor(p, 32, 64);
        if (lane < 16) sLog[bloc * 33 + j] = p;
      }
      __syncthreads();
      const float* logrow = &sLog[bloc * 33];
      float ssum = 0.f;
      #pragma unroll
      for (int jj = 0; jj < 32; ++jj) ssum += __expf(logrow[jj]);
      float inv = 1.0f / ssum;
      #pragma unroll
      for (int tj = 0; tj < 16; ++tj){
        int j = jhalf * 16 + tj;
        short8 al8 = *(const short8*)(&sW[buf][j * 256 + lb * 16 + q1 * 8]);
        short8 afrag = (lq < 2) ? al8 : zero8;
        f32x4 u = __builtin_amdgcn_mfma_f32_16x16x32_bf16(afrag, bfrag, zf4, 0, 0, 0);
        float c = __expf(logrow[j]) * inv;
        acc[tj].x += c * u.x; acc[tj].y += c * u.y;
        acc[tj].z += c * u.z; acc[tj].w += c * u.w;
      }
    }
    if (more){
      const int nb = buf ^ 1;
      #pragma unroll
      for (int r = 0; r < 4; ++r){
        int c = r * 256 + t;
        *(uint4v*)(&sW[nb][c * 8]) = cvt8(wpa[r], wpb[r]);
      }
      sXd[nb][t] = packbf2(xp.x, xp.y);
    }
    __syncthreads();
  }
  float* dst = partials + ((size_t)blockIdx.x * 4 + (size_t)w) * 4096 + (size_t)lane * 64;
  #pragma unroll
  for (int tj = 0; tj < 16; ++tj) *(f32x4*)(dst + tj * 4) = acc[tj];
}

template<int NBLK>
__global__ __launch_bounds__(128)
void caps_reduce(const float* __restrict__ partials, float* __restrict__ S_buf, float scale)
{
  const int T = blockIdx.x * 128 + threadIdx.x;
  float s0 = 0.f, s1 = 0.f, s2 = 0.f, s3 = 0.f;
  #pragma unroll 4
  for (int bl = 0; bl < NBLK; bl += 4){
    s0 += partials[(size_t)(bl + 0) * 32768 + T];
    s1 += partials[(size_t)(bl + 1) * 32768 + T];
    s2 += partials[(size_t)(bl + 2) * 32768 + T];
    s3 += partials[(size_t)(bl + 3) * 32768 + T];
  }
  float s = ((s0 + s1) + (s2 + s3)) * scale;
  const int bhalf = T >> 14, w = (T >> 12) & 3, l = (T >> 6) & 63, k = T & 63;
  const int b  = bhalf * 32 + (w & 1) * 16 + (l & 15);
  const int jd = ((w >> 1) * 16 + (k >> 2)) * 16 + ((l >> 4) << 2) + (k & 3);
  S_buf[b * 512 + jd] = s;
}

__global__ __launch_bounds__(256)
void caps_squash_j(const float* __restrict__ S, const float* __restrict__ vprev,
                   float* __restrict__ vout)
{
  const int b = blockIdx.x, t = threadIdx.x;
  __shared__ float sq[16];
  if (t < 16) sq[t] = 0.f;
  __syncthreads();
  float s0 = S[b * 512 + t], s1 = S[b * 512 + 256 + t];
  atomicAdd(&sq[t & 15], s0 * s0 + s1 * s1);
  __syncthreads();
  float q = sq[t & 15];
  float f = q / ((1.f + q) * sqrtf(q + 1e-8f));
  float v0 = s0 * f, v1 = s1 * f;
  if (vprev){ v0 += vprev[b * 512 + t]; v1 += vprev[b * 512 + 256 + t]; }
  vout[b * 512 + t] = v0;
  vout[b * 512 + 256 + t] = v1;
}

__global__ __launch_bounds__(256)
void caps_squash_d(const float* __restrict__ S, float* __restrict__ out)
{
  const int b = blockIdx.x, t = threadIdx.x;
  __shared__ float sq[32];
  if (t < 32) sq[t] = 0.f;
  __syncthreads();
  float s0 = S[b * 512 + t], s1 = S[b * 512 + 256 + t];
  atomicAdd(&sq[t >> 4], s0 * s0);
  atomicAdd(&sq[(t + 256) >> 4], s1 * s1);
  __syncthreads();
  float q0 = sq[t >> 4], q1 = sq[(t + 256) >> 4];
  out[b * 512 + t]       = s0 * q0 / ((1.f + q0) * sqrtf(q0 + 1e-8f));
  out[b * 512 + 256 + t] = s1 * q1 / ((1.f + q1) * sqrtf(q1 + 1e-8f));
}

extern "C" void kernel_launch(void* const* d_in, const int* in_sizes, int n_in,
                              void* d_out, int out_size, void* d_ws, size_t ws_size,
                              hipStream_t stream)
{
  const float* X = (const float*)d_in[0];  // fp32 [64][2048][16]
  const float* W = (const float*)d_in[1];  // fp32 [2048][32][16][16]
  float* wsf = (float*)d_ws;
  float* outp = (float*)d_out;

  const size_t WB_ELE = (size_t)NI * 8192, XB_ELE = (size_t)NI * 64 * 16;
  const size_t FP = (size_t)256 * 32768;   // partial planes (256 iblk) x 32768
  const size_t need_full = (FP + 3 * 32768) * 4 + (WB_ELE + XB_ELE) * 2;

  if (ws_size >= need_full){
    float* partials = wsf;
    float* sbuf = wsf + FP;
    float* v1   = sbuf + 32768;
    float* v12  = v1 + 32768;
    u16* Wb = (u16*)(v12 + 32768);
    u16* Xb = Wb + WB_ELE;

    // --- preferred: single cooperative kernel (512 blocks, 2/CU) ---
    {
      const float* Wa = W; const float* Xa = X;
      u16* Wba = Wb; u16* Xba = Xb;
      float* pa = partials; float* sa = sbuf; float* oa = outp;
      void* args[] = { (void*)&Wa, (void*)&Xa, (void*)&Wba, (void*)&Xba,
                       (void*)&pa, (void*)&sa, (void*)&oa };
      hipError_t err = hipLaunchCooperativeKernel(
          reinterpret_cast<void*>(caps_fused), dim3(512), dim3(256),
          args, 0, stream);
      if (err == hipSuccess) return;
      (void)hipGetLastError();   // clear, fall through to multi-kernel path
    }

    // --- fallback: round-5 multi-kernel path (proven 233 us) ---
    caps_prep<<<dim3(8704), dim3(256), 0, stream>>>(W, X, Wb, Xb);

    caps_pass_mk<0><<<dim3(512), dim3(256), 0, stream>>>(Wb, Xb, nullptr, partials, 8);
    caps_reduce<256><<<dim3(256), dim3(128), 0, stream>>>(partials, sbuf, 1.0f / 32.0f);
    caps_squash_j<<<dim3(64), dim3(256), 0, stream>>>(sbuf, nullptr, v1);

    caps_pass_mk<1><<<dim3(512), dim3(256), 0, stream>>>(Wb, Xb, v1, partials, 8);
    caps_reduce<256><<<dim3(256), dim3(128), 0, stream>>>(partials, sbuf, 1.0f);
    caps_squash_j<<<dim3(64), dim3(256), 0, stream>>>(sbuf, v1, v12);

    caps_pass_mk<1><<<dim3(512), dim3(256), 0, stream>>>(Wb, Xb, v12, partials, 8);
    caps_reduce<256><<<dim3(256), dim3(128), 0, stream>>>(partials, sbuf, 1.0f);
    caps_squash_d<<<dim3(64), dim3(256), 0, stream>>>(sbuf, outp);
  } else {
    // legacy fp32-input ladder for tiny ws
    int nbi = 256;
    auto need = [](int nb){ return ((size_t)nb * 32768 + 3 * 32768) * 4; };
    if (ws_size < need(256)){
      if      (ws_size >= need(64)) nbi = 64;
      else if (ws_size >= need(16)) nbi = 16;
      else                          nbi = 4;
    }
    const int CI = NI / nbi;
    float* partials = wsf;
    float* sbuf = wsf + (size_t)nbi * 32768;
    float* v1   = sbuf + 32768;
    float* v12  = v1 + 32768;
    auto reduce = [&](float scale){
      if      (nbi == 256) caps_reduce<256><<<dim3(256), dim3(128), 0, stream>>>(partials, sbuf, scale);
      else if (nbi ==  64) caps_reduce< 64><<<dim3(256), dim3(128), 0, stream>>>(partials, sbuf, scale);
      else if (nbi ==  16) caps_reduce< 16><<<dim3(256), dim3(128), 0, stream>>>(partials, sbuf, scale);
      else                 caps_reduce<  4><<<dim3(256), dim3(128), 0, stream>>>(partials, sbuf, scale);
    };
    caps_pass_legacy<0><<<dim3(2 * nbi), dim3(256), 0, stream>>>(W, X, nullptr, partials, CI);
    reduce(1.0f / 32.0f);
    caps_squash_j<<<dim3(64), dim3(256), 0, stream>>>(sbuf, nullptr, v1);
    caps_pass_legacy<1><<<dim3(2 * nbi), dim3(256), 0, stream>>>(W, X, v1, partials, CI);
    reduce(1.0f);
    caps_squash_j<<<dim3(64), dim3(256), 0, stream>>>(sbuf, v1, v12);
    caps_pass_legacy<1><<<dim3(2 * nbi), dim3(256), 0, stream>>>(W, X, v12, partials, CI);
    reduce(1.0f);
    caps_squash_d<<<dim3(64), dim3(256), 0, stream>>>(sbuf, outp);
  }
}

// Round 8
// 280.871 us; speedup vs baseline: 3.7919x; 3.7919x over previous
//
#include <hip/hip_runtime.h>

typedef __attribute__((ext_vector_type(8))) short short8;
typedef __attribute__((ext_vector_type(16))) float f32x16;
typedef __attribute__((ext_vector_type(4))) float f32x4;
typedef __attribute__((ext_vector_type(2))) float f32x2;
typedef __attribute__((ext_vector_type(4))) unsigned int uint4v;
typedef unsigned short u16;

#define NI 2048   // input capsules
// B=64, J=32, D=16, E=16, JD=512. Inputs fp32; compute bf16 MFMA 32x32x16 (K=E, no waste).

__device__ __forceinline__ unsigned int packbf2(float a, float b){
  unsigned int ua = __float_as_uint(a), ub = __float_as_uint(b);
  unsigned int ra = (ua + 0x7FFFu + ((ua >> 16) & 1u)) >> 16;
  unsigned int rb = (ub + 0x7FFFu + ((ub >> 16) & 1u)) & 0xFFFF0000u;
  return ra | rb;
}
__device__ __forceinline__ float bflo(unsigned int p){ return __uint_as_float(p << 16); }
__device__ __forceinline__ float bfhi(unsigned int p){ return __uint_as_float(p & 0xFFFF0000u); }

__device__ __forceinline__ uint4v cvt8(const f32x4& a, const f32x4& b){
  uint4v p = { packbf2(a.x, a.y), packbf2(a.z, a.w),
               packbf2(b.x, b.y), packbf2(b.z, b.w) };
  return p;
}

__device__ __forceinline__ void gl_lds16(const void* g, void* l){
  __builtin_amdgcn_global_load_lds(
      (const __attribute__((address_space(1))) unsigned int*)g,
      (__attribute__((address_space(3))) unsigned int*)l, 16, 0, 0);
}

// ---------------- prep: W fp32->bf16 (same layout), X fp32->bf16 transposed to [i][b][e]
__global__ __launch_bounds__(256)
void caps_prep(const float* __restrict__ W, const float* __restrict__ X,
               u16* __restrict__ Wb, u16* __restrict__ Xb)
{
  const int bid = blockIdx.x;
  if (bid < 8192){
    size_t base = (size_t)bid * 2048 + (size_t)threadIdx.x * 8;
    f32x4 a = *(const f32x4*)(W + base);
    f32x4 b = *(const f32x4*)(W + base + 4);
    *(uint4v*)(Wb + base) = cvt8(a, b);
  } else {
    int p = (bid - 8192) * 256 + threadIdx.x;   // 0..131071 = (i,b)
    int i = p >> 6, b = p & 63;
    const float* src = X + ((size_t)b * NI + i) * 16;
    f32x4 a0 = *(const f32x4*)(src);
    f32x4 a1 = *(const f32x4*)(src + 4);
    f32x4 a2 = *(const f32x4*)(src + 8);
    f32x4 a3 = *(const f32x4*)(src + 12);
    *(uint4v*)(Xb + (size_t)p * 16)     = cvt8(a0, a1);
    *(uint4v*)(Xb + (size_t)p * 16 + 8) = cvt8(a2, a3);
  }
}

// ---------------- 32x32x16 pass
// Block: 256 thr = 4 waves; wave w owns j = w*8..w*8+7 (4 tiles x 2 j), all 32
// block-b's (bhalf = blockIdx.x&1). Tile: M=32 rows = 2 j x 16 d, N=32 b, K=16 e.
// A frag: m=lane&31 -> (j_off=m>>4, d=m&15), k=hi*8+i.  B frag: n=lane&31=b, k=hi*8+i.
// C/D: col=lane&31=b, row=(r&3)+8*(r>>2)+4*hi -> j_off=(r>=8), d=(r&3)+8*((r>>2)&1)+4*hi.
// MODE 0: uniform c -> partials of sum_i u
// MODE 1: c = softmax_j(u.v); v computed per-thread from S1 (+S2) at kernel start.
template<int MODE>
__global__ __launch_bounds__(256, (MODE == 0) ? 4 : 2)
void caps_pass32(const u16* __restrict__ Wb,   // bf16 [NI][8192] (j*256+d*16+e)
                 const u16* __restrict__ Xb,   // bf16 [NI][64][16]
                 const float* __restrict__ S1, // [64][512] (MODE 1)
                 const float* __restrict__ S2, // [64][512] or null (MODE 1, pass C)
                 float* __restrict__ partials)
{
  __shared__ __align__(16) u16 sW[2][8192];
  __shared__ __align__(16) u16 sX[2][512];
  __shared__ float sSum[4][32];

  const int t     = threadIdx.x;
  const int w     = t >> 6;
  const int lane  = t & 63;
  const int bl    = lane & 31;          // b within block / tile col
  const int hi    = lane >> 5;          // k-half / row offset
  const int bhalf = blockIdx.x & 1;
  const int iblk  = blockIdx.x >> 1;
  const int i0    = iblk * 8;           // 8 i-rows per block

  const f32x16 z16 = {0,0,0,0,0,0,0,0,0,0,0,0,0,0,0,0};

  f32x16 acc[4];
  #pragma unroll
  for (int tt = 0; tt < 4; ++tt) acc[tt] = z16;

  // v packed bf16: vpk[jj][q] = (d-pair 2q,2q+1) of v[b][w*8+jj][d(r,hi)],
  // d(r,hi) = (r&3)+8*(r>>2)+4*hi for r=0..7
  unsigned int vpk[8][4];
  if constexpr (MODE == 1){
    auto vcomp = [&](const float* S, bool addprev){
      const float* Srow = S + (bhalf * 32 + bl) * 512 + 4 * hi;
      f32x4 sqA = {0,0,0,0}, sqB = {0,0,0,0};
      #pragma unroll 8
      for (int j = 0; j < 32; ++j){
        f32x4 a  = *(const f32x4*)(Srow + j * 16);
        f32x4 b4 = *(const f32x4*)(Srow + j * 16 + 8);
        sqA.x += a.x * a.x;  sqA.y += a.y * a.y;
        sqA.z += a.z * a.z;  sqA.w += a.w * a.w;
        sqB.x += b4.x * b4.x; sqB.y += b4.y * b4.y;
        sqB.z += b4.z * b4.z; sqB.w += b4.w * b4.w;
      }
      f32x4 fA, fB;
      fA.x = sqA.x / ((1.f + sqA.x) * sqrtf(sqA.x + 1e-8f));
      fA.y = sqA.y / ((1.f + sqA.y) * sqrtf(sqA.y + 1e-8f));
      fA.z = sqA.z / ((1.f + sqA.z) * sqrtf(sqA.z + 1e-8f));
      fA.w = sqA.w / ((1.f + sqA.w) * sqrtf(sqA.w + 1e-8f));
      fB.x = sqB.x / ((1.f + sqB.x) * sqrtf(sqB.x + 1e-8f));
      fB.y = sqB.y / ((1.f + sqB.y) * sqrtf(sqB.y + 1e-8f));
      fB.z = sqB.z / ((1.f + sqB.z) * sqrtf(sqB.z + 1e-8f));
      fB.w = sqB.w / ((1.f + sqB.w) * sqrtf(sqB.w + 1e-8f));
      #pragma unroll
      for (int jj = 0; jj < 8; ++jj){
        int j = w * 8 + jj;
        f32x4 a  = *(const f32x4*)(Srow + j * 16);
        f32x4 b4 = *(const f32x4*)(Srow + j * 16 + 8);
        float v0 = a.x * fA.x,  v1 = a.y * fA.y,  v2 = a.z * fA.z,  v3 = a.w * fA.w;
        float v4 = b4.x * fB.x, v5 = b4.y * fB.y, v6 = b4.z * fB.z, v7 = b4.w * fB.w;
        if (addprev){
          v0 += bflo(vpk[jj][0]); v1 += bfhi(vpk[jj][0]);
          v2 += bflo(vpk[jj][1]); v3 += bfhi(vpk[jj][1]);
          v4 += bflo(vpk[jj][2]); v5 += bfhi(vpk[jj][2]);
          v6 += bflo(vpk[jj][3]); v7 += bfhi(vpk[jj][3]);
        }
        vpk[jj][0] = packbf2(v0, v1);
        vpk[jj][1] = packbf2(v2, v3);
        vpk[jj][2] = packbf2(v4, v5);
        vpk[jj][3] = packbf2(v6, v7);
      }
    };
    vcomp(S1, false);
    if (S2) vcomp(S2, true);    // v12 = v1 + squash(S2)
  }

  // async stage of row irow into buffer nb: W 16 KB (4 waves x 4 x 1 KB), X 1 KB
  auto stage = [&](int nb, int irow){
    const u16* src = Wb + (size_t)irow * 8192 + (size_t)(w * 4) * 512;
    u16* dst = &sW[nb][w * 4 * 512];
    #pragma unroll
    for (int r = 0; r < 4; ++r)
      gl_lds16(src + r * 512 + lane * 8, dst + r * 512);
    if (w == 3)
      gl_lds16(Xb + ((size_t)irow * 64 + bhalf * 32) * 16 + lane * 8, &sX[nb][0]);
  };

  stage(0, i0);
  __syncthreads();

  for (int s = 0; s < 8; ++s){
    const int buf = s & 1;
    if (s + 1 < 8) stage(buf ^ 1, i0 + s + 1);   // async, drained by barrier

    short8 bfrag = *(const short8*)(&sX[buf][bl * 16 + hi * 8]);

    if constexpr (MODE == 0){
      #pragma unroll
      for (int tt = 0; tt < 4; ++tt){
        const int je = w * 8 + tt * 2 + (bl >> 4);
        short8 afrag = *(const short8*)(&sW[buf][je * 256 + (bl & 15) * 16 + hi * 8]);
        acc[tt] = __builtin_amdgcn_mfma_f32_32x32x16_bf16(afrag, bfrag, acc[tt], 0, 0, 0);
      }
    } else {
      f32x16 ut[4];
      float e[8];
      #pragma unroll
      for (int tt = 0; tt < 4; ++tt){
        const int je = w * 8 + tt * 2 + (bl >> 4);
        short8 afrag = *(const short8*)(&sW[buf][je * 256 + (bl & 15) * 16 + hi * 8]);
        ut[tt] = __builtin_amdgcn_mfma_f32_32x32x16_bf16(afrag, bfrag, z16, 0, 0, 0);
        float p0 = ut[tt][0] * bflo(vpk[2*tt][0]) + ut[tt][1] * bfhi(vpk[2*tt][0])
                 + ut[tt][2] * bflo(vpk[2*tt][1]) + ut[tt][3] * bfhi(vpk[2*tt][1])
                 + ut[tt][4] * bflo(vpk[2*tt][2]) + ut[tt][5] * bfhi(vpk[2*tt][2])
                 + ut[tt][6] * bflo(vpk[2*tt][3]) + ut[tt][7] * bfhi(vpk[2*tt][3]);
        float p1 = ut[tt][8]  * bflo(vpk[2*tt+1][0]) + ut[tt][9]  * bfhi(vpk[2*tt+1][0])
                 + ut[tt][10] * bflo(vpk[2*tt+1][1]) + ut[tt][11] * bfhi(vpk[2*tt+1][1])
                 + ut[tt][12] * bflo(vpk[2*tt+1][2]) + ut[tt][13] * bfhi(vpk[2*tt+1][2])
                 + ut[tt][14] * bflo(vpk[2*tt+1][3]) + ut[tt][15] * bfhi(vpk[2*tt+1][3]);
        p0 += __shfl_xor(p0, 32, 64);   // combine hi halves (d 0..7 | 8..15 coverage)
        p1 += __shfl_xor(p1, 32, 64);
        e[2*tt]   = __expf(p0);         // |logit| small -> fp32-safe w/o max-sub
        e[2*tt+1] = __expf(p1);
      }
      float ps = ((e[0] + e[1]) + (e[2] + e[3])) + ((e[4] + e[5]) + (e[6] + e[7]));
      if (lane < 32) sSum[w][lane] = ps;
      __syncthreads();
      float inv = 1.0f / (((sSum[0][bl] + sSum[1][bl]) + (sSum[2][bl] + sSum[3][bl])));
      #pragma unroll
      for (int tt = 0; tt < 4; ++tt){
        float c0 = e[2*tt] * inv, c1 = e[2*tt+1] * inv;
        #pragma unroll
        for (int r = 0; r < 8; ++r){
          acc[tt][r]     += c0 * ut[tt][r];
          acc[tt][r + 8] += c1 * ut[tt][r + 8];
        }
      }
    }
    __syncthreads();
  }

  float* dst = partials + (size_t)blockIdx.x * 16384 + (size_t)w * 4096 + (size_t)lane * 64;
  #pragma unroll
  for (int tt = 0; tt < 4; ++tt){
    #pragma unroll
    for (int q = 0; q < 4; ++q){
      f32x4 v = { acc[tt][q*4+0], acc[tt][q*4+1], acc[tt][q*4+2], acc[tt][q*4+3] };
      *(f32x4*)(dst + tt * 16 + q * 4) = v;
    }
  }
}

// reduce 256 planes -> S_buf[b][jd] (32x32-tile un-permute)
__global__ __launch_bounds__(128)
void caps_reduce32(const float* __restrict__ partials, float* __restrict__ S_buf, float scale)
{
  const int T = blockIdx.x * 128 + threadIdx.x;   // 0..32767
  float s0 = 0.f, s1 = 0.f, s2 = 0.f, s3 = 0.f;
  #pragma unroll 4
  for (int bl = 0; bl < 256; bl += 4){
    s0 += partials[(size_t)(bl + 0) * 32768 + T];
    s1 += partials[(size_t)(bl + 1) * 32768 + T];
    s2 += partials[(size_t)(bl + 2) * 32768 + T];
    s3 += partials[(size_t)(bl + 3) * 32768 + T];
  }
  float s = ((s0 + s1) + (s2 + s3)) * scale;
  const int bhalf = T >> 14, w = (T >> 12) & 3, l = (T >> 6) & 63, k = T & 63;
  const int tt = k >> 4, r = k & 15;
  const int b  = bhalf * 32 + (l & 31);
  const int hi = l >> 5;
  const int j  = w * 8 + tt * 2 + (r >> 3);
  const int d  = (r & 3) + 8 * ((r >> 2) & 1) + 4 * hi;
  S_buf[b * 512 + j * 16 + d] = s;
}

// final squash over D (axis=-1): fp32 output [B][J][D]
__global__ __launch_bounds__(256)
void caps_squash_d(const float* __restrict__ S, float* __restrict__ out)
{
  const int b = blockIdx.x, t = threadIdx.x;
  __shared__ float sq[32];
  if (t < 32) sq[t] = 0.f;
  __syncthreads();
  float s0 = S[b * 512 + t], s1 = S[b * 512 + 256 + t];
  atomicAdd(&sq[t >> 4], s0 * s0);
  atomicAdd(&sq[(t + 256) >> 4], s1 * s1);
  __syncthreads();
  float q0 = sq[t >> 4], q1 = sq[(t + 256) >> 4];
  out[b * 512 + t]       = s0 * q0 / ((1.f + q0) * sqrtf(q0 + 1e-8f));
  out[b * 512 + 256 + t] = s1 * q1 / ((1.f + q1) * sqrtf(q1 + 1e-8f));
}

// ======================= legacy fp32-input fallback (small ws) =======================
template<int MODE>
__global__ __launch_bounds__(256)
void caps_pass_legacy(const float* __restrict__ Wg, const float* __restrict__ Xg,
                      const float* __restrict__ vbuf, float* __restrict__ partials, int CI)
{
  typedef __attribute__((ext_vector_type(4))) float f4;
  __shared__ __align__(16) unsigned short sW[2][8192];
  __shared__ __align__(16) unsigned int   sXd[2][256];
  __shared__ float sLog[(MODE == 1) ? (32 * 33) : 4];
  const int t = threadIdx.x, w = t >> 6, lane = t & 63;
  const int wtile = w & 1, jhalf = w >> 1, lq = lane >> 4, lb = lane & 15, q1 = lq & 1;
  const int bhalf = blockIdx.x & 1, iblk = blockIdx.x >> 1;
  const int bloc = wtile * 16 + lb, bg = bhalf * 32 + bloc;
  const size_t i0 = (size_t)iblk * (size_t)CI;
  const short8 zero8 = {0,0,0,0,0,0,0,0};
  const f4 zf4 = {0.f,0.f,0.f,0.f};
  f4 acc[16];
  #pragma unroll
  for (int tj = 0; tj < 16; ++tj) acc[tj] = zf4;
  unsigned int vpl[16], vph[16];
  if constexpr (MODE == 1){
    #pragma unroll
    for (int tj = 0; tj < 16; ++tj){
      f4 v = *(const f4*)(&vbuf[bg * 512 + (jhalf * 16 + tj) * 16 + lq * 4]);
      vpl[tj] = packbf2(v.x, v.y); vph[tj] = packbf2(v.z, v.w);
    }
  }
  {
    const float* wsrc = Wg + i0 * 8192;
    #pragma unroll
    for (int r = 0; r < 4; ++r){
      int c = r * 256 + t;
      f4 a = *(const f4*)(&wsrc[c * 8]);
      f4 b = *(const f4*)(&wsrc[c * 8 + 4]);
      *(uint4v*)(&sW[0][c * 8]) = cvt8(a, b);
    }
    int bidx = bhalf * 32 + (t >> 3), e2 = t & 7;
    f32x2 xv = *(const f32x2*)(&Xg[((size_t)bidx * NI + i0) * 16 + e2 * 2]);
    sXd[0][t] = packbf2(xv.x, xv.y);
  }
  __syncthreads();
  for (int s = 0; s < CI; ++s){
    const int buf = s & 1;
    f4 wpa[4], wpb[4]; f32x2 xp;
    const bool more = (s + 1 < CI);
    if (more){
      const float* wsrc = Wg + (i0 + (size_t)(s + 1)) * 8192;
      #pragma unroll
      for (int r = 0; r < 4; ++r){
        int c = r * 256 + t;
        wpa[r] = *(const f4*)(&wsrc[c * 8]);
        wpb[r] = *(const f4*)(&wsrc[c * 8 + 4]);
      }
      int bidx = bhalf * 32 + (t >> 3), e2 = t & 7;
      xp = *(const f32x2*)(&Xg[((size_t)bidx * NI + i0 + s + 1) * 16 + e2 * 2]);
    }
    const unsigned short* xrow = (const unsigned short*)&sXd[buf][0];
    short8 bl8 = *(const short8*)(&xrow[bloc * 16 + q1 * 8]);
    short8 bfrag = (lq < 2) ? bl8 : zero8;
    if constexpr (MODE == 0){
      #pragma unroll
      for (int tj = 0; tj < 16; ++tj){
        int j = jhalf * 16 + tj;
        short8 al8 = *(const short8*)(&sW[buf][j * 256 + lb * 16 + q1 * 8]);
        short8 afrag = (lq < 2) ? al8 : zero8;
        acc[tj] = __builtin_amdgcn_mfma_f32_16x16x32_bf16(afrag, bfrag, acc[tj], 0, 0, 0);
      }
    } else {
      #pragma unroll
      for (int tj = 0; tj < 16; ++tj){
        int j = jhalf * 16 + tj;
        short8 al8 = *(const short8*)(&sW[buf][j * 256 + lb * 16 + q1 * 8]);
        short8 afrag = (lq < 2) ? al8 : zero8;
        f4 u = __builtin_amdgcn_mfma_f32_16x16x32_bf16(afrag, bfrag, zf4, 0, 0, 0);
        float p = u.x * bflo(vpl[tj]) + u.y * bfhi(vpl[tj])
                + u.z * bflo(vph[tj]) + u.w * bfhi(vph[tj]);
        p += __shfl_xor(p, 16, 64);
        p += __shfl_xor(p, 32, 64);
        if (lane < 16) sLog[bloc * 33 + j] = p;
      }
      __syncthreads();
      const float* logrow = &sLog[bloc * 33];
      float ssum = 0.f;
      #pragma unroll
      for (int jj = 0; jj < 32; ++jj) ssum += __expf(logrow[jj]);
      float inv = 1.0f / ssum;
      #pragma unroll
      for (int tj = 0; tj < 16; ++tj){
        int j = jhalf * 16 + tj;
        short8 al8 = *(const short8*)(&sW[buf][j * 256 + lb * 16 + q1 * 8]);
        short8 afrag = (lq < 2) ? al8 : zero8;
        f4 u = __builtin_amdgcn_mfma_f32_16x16x32_bf16(afrag, bfrag, zf4, 0, 0, 0);
        float c = __expf(logrow[j]) * inv;
        acc[tj].x += c * u.x; acc[tj].y += c * u.y;
        acc[tj].z += c * u.z; acc[tj].w += c * u.w;
      }
    }
    if (more){
      const int nb = buf ^ 1;
      #pragma unroll
      for (int r = 0; r < 4; ++r){
        int c = r * 256 + t;
        *(uint4v*)(&sW[nb][c * 8]) = cvt8(wpa[r], wpb[r]);
      }
      sXd[nb][t] = packbf2(xp.x, xp.y);
    }
    __syncthreads();
  }
  float* dst = partials + ((size_t)blockIdx.x * 4 + (size_t)w) * 4096 + (size_t)lane * 64;
  #pragma unroll
  for (int tj = 0; tj < 16; ++tj) *(f4*)(dst + tj * 4) = acc[tj];
}

template<int NBLK>
__global__ __launch_bounds__(128)
void caps_reduce_legacy(const float* __restrict__ partials, float* __restrict__ S_buf, float scale)
{
  const int T = blockIdx.x * 128 + threadIdx.x;
  float s0 = 0.f, s1 = 0.f, s2 = 0.f, s3 = 0.f;
  #pragma unroll 4
  for (int bl = 0; bl < NBLK; bl += 4){
    s0 += partials[(size_t)(bl + 0) * 32768 + T];
    s1 += partials[(size_t)(bl + 1) * 32768 + T];
    s2 += partials[(size_t)(bl + 2) * 32768 + T];
    s3 += partials[(size_t)(bl + 3) * 32768 + T];
  }
  float s = ((s0 + s1) + (s2 + s3)) * scale;
  const int bhalf = T >> 14, w = (T >> 12) & 3, l = (T >> 6) & 63, k = T & 63;
  const int b  = bhalf * 32 + (w & 1) * 16 + (l & 15);
  const int jd = ((w >> 1) * 16 + (k >> 2)) * 16 + ((l >> 4) << 2) + (k & 3);
  S_buf[b * 512 + jd] = s;
}

__global__ __launch_bounds__(256)
void caps_squash_j(const float* __restrict__ S, const float* __restrict__ vprev,
                   float* __restrict__ vout)
{
  const int b = blockIdx.x, t = threadIdx.x;
  __shared__ float sq[16];
  if (t < 16) sq[t] = 0.f;
  __syncthreads();
  float s0 = S[b * 512 + t], s1 = S[b * 512 + 256 + t];
  atomicAdd(&sq[t & 15], s0 * s0 + s1 * s1);
  __syncthreads();
  float q = sq[t & 15];
  float f = q / ((1.f + q) * sqrtf(q + 1e-8f));
  float v0 = s0 * f, v1 = s1 * f;
  if (vprev){ v0 += vprev[b * 512 + t]; v1 += vprev[b * 512 + 256 + t]; }
  vout[b * 512 + t] = v0;
  vout[b * 512 + 256 + t] = v1;
}

extern "C" void kernel_launch(void* const* d_in, const int* in_sizes, int n_in,
                              void* d_out, int out_size, void* d_ws, size_t ws_size,
                              hipStream_t stream)
{
  const float* X = (const float*)d_in[0];  // fp32 [64][2048][16]
  const float* W = (const float*)d_in[1];  // fp32 [2048][32][16][16]
  float* wsf = (float*)d_ws;
  float* outp = (float*)d_out;

  const size_t WB_ELE = (size_t)NI * 8192, XB_ELE = (size_t)NI * 64 * 16;
  const size_t FP = (size_t)256 * 32768;   // partials: 256 planes x 32768 floats
  const size_t need_full = (FP + 3 * 32768) * 4 + (WB_ELE + XB_ELE) * 2;

  if (ws_size >= need_full){
    float* partials = wsf;
    float* S1 = wsf + FP;
    float* S2 = S1 + 32768;
    float* S3 = S2 + 32768;
    u16* Wb = (u16*)(S3 + 32768);
    u16* Xb = Wb + WB_ELE;

    caps_prep<<<dim3(8704), dim3(256), 0, stream>>>(W, X, Wb, Xb);

    // pass A (uniform c) -> S1
    caps_pass32<0><<<dim3(512), dim3(256), 0, stream>>>(Wb, Xb, nullptr, nullptr, partials);
    caps_reduce32<<<dim3(256), dim3(128), 0, stream>>>(partials, S1, 1.0f / 32.0f);
    // pass B: v1 = squash_J(S1) computed in-kernel -> S2
    caps_pass32<1><<<dim3(512), dim3(256), 0, stream>>>(Wb, Xb, S1, nullptr, partials);
    caps_reduce32<<<dim3(256), dim3(128), 0, stream>>>(partials, S2, 1.0f);
    // pass C: v12 = squash_J(S1) + squash_J(S2) in-kernel -> S3
    caps_pass32<1><<<dim3(512), dim3(256), 0, stream>>>(Wb, Xb, S1, S2, partials);
    caps_reduce32<<<dim3(256), dim3(128), 0, stream>>>(partials, S3, 1.0f);
    caps_squash_d<<<dim3(64), dim3(256), 0, stream>>>(S3, outp);
  } else {
    // legacy fp32-input ladder for tiny ws
    int nbi = 256;
    auto need = [](int nb){ return ((size_t)nb * 32768 + 3 * 32768) * 4; };
    if (ws_size < need(256)){
      if      (ws_size >= need(64)) nbi = 64;
      else if (ws_size >= need(16)) nbi = 16;
      else                          nbi = 4;
    }
    const int CI = NI / nbi;
    float* partials = wsf;
    float* sbuf = wsf + (size_t)nbi * 32768;
    float* v1   = sbuf + 32768;
    float* v12  = v1 + 32768;
    auto reduce = [&](float scale){
      if      (nbi == 256) caps_reduce_legacy<256><<<dim3(256), dim3(128), 0, stream>>>(partials, sbuf, scale);
      else if (nbi ==  64) caps_reduce_legacy< 64><<<dim3(256), dim3(128), 0, stream>>>(partials, sbuf, scale);
      else if (nbi ==  16) caps_reduce_legacy< 16><<<dim3(256), dim3(128), 0, stream>>>(partials, sbuf, scale);
      else                 caps_reduce_legacy<  4><<<dim3(256), dim3(128), 0, stream>>>(partials, sbuf, scale);
    };
    caps_pass_legacy<0><<<dim3(2 * nbi), dim3(256), 0, stream>>>(W, X, nullptr, partials, CI);
    reduce(1.0f / 32.0f);
    caps_squash_j<<<dim3(64), dim3(256), 0, stream>>>(sbuf, nullptr, v1);
    caps_pass_legacy<1><<<dim3(2 * nbi), dim3(256), 0, stream>>>(W, X, v1, partials, CI);
    reduce(1.0f);
    caps_squash_j<<<dim3(64), dim3(256), 0, stream>>>(sbuf, v1, v12);
    caps_pass_legacy<1><<<dim3(2 * nbi), dim3(256), 0, stream>>>(W, X, v12, partials, CI);
    reduce(1.0f);
    caps_squash_d<<<dim3(64), dim3(256), 0, stream>>>(sbuf, outp);
  }
}

// Round 9
// 272.159 us; speedup vs baseline: 3.9133x; 1.0320x over previous
//
#include <hip/hip_runtime.h>

typedef __attribute__((ext_vector_type(8))) short short8;
typedef __attribute__((ext_vector_type(4))) float f32x4;
typedef __attribute__((ext_vector_type(2))) float f32x2;
typedef __attribute__((ext_vector_type(4))) unsigned int uint4v;
typedef unsigned short u16;

#define NI 2048   // input capsules
// B=64, J=32, D=16, E=16, JD=512. Inputs fp32; compute bf16 MFMA 16x16x32.

// bf16 RNE pack of two floats -> dword (lo=a, hi=b)
__device__ __forceinline__ unsigned int packbf2(float a, float b){
  unsigned int ua = __float_as_uint(a), ub = __float_as_uint(b);
  unsigned int ra = (ua + 0x7FFFu + ((ua >> 16) & 1u)) >> 16;
  unsigned int rb = (ub + 0x7FFFu + ((ub >> 16) & 1u)) & 0xFFFF0000u;
  return ra | rb;
}
__device__ __forceinline__ float bflo(unsigned int p){ return __uint_as_float(p << 16); }
__device__ __forceinline__ float bfhi(unsigned int p){ return __uint_as_float(p & 0xFFFF0000u); }

__device__ __forceinline__ uint4v cvt8(const f32x4& a, const f32x4& b){
  uint4v p = { packbf2(a.x, a.y), packbf2(a.z, a.w),
               packbf2(b.x, b.y), packbf2(b.z, b.w) };
  return p;
}

// async global->LDS, 16 B per lane; lds dest = wave-uniform base (+ implicit lane*16)
__device__ __forceinline__ void gl_lds16(const void* g, void* l){
  __builtin_amdgcn_global_load_lds(
      (const __attribute__((address_space(1))) unsigned int*)g,
      (__attribute__((address_space(3))) unsigned int*)l, 16, 0, 0);
}

// ---------------- prep: W fp32->bf16 (same layout), X fp32->bf16 transposed to [i][b][e]
__global__ __launch_bounds__(256)
void caps_prep(const float* __restrict__ W, const float* __restrict__ X,
               u16* __restrict__ Wb, u16* __restrict__ Xb)
{
  const int bid = blockIdx.x;
  if (bid < 8192){
    size_t base = (size_t)bid * 2048 + (size_t)threadIdx.x * 8;
    f32x4 a = *(const f32x4*)(W + base);
    f32x4 b = *(const f32x4*)(W + base + 4);
    *(uint4v*)(Wb + base) = cvt8(a, b);
  } else {
    int p = (bid - 8192) * 256 + threadIdx.x;   // 0..131071 = (i,b)
    int i = p >> 6, b = p & 63;
    const float* src = X + ((size_t)b * NI + i) * 16;
    f32x4 a0 = *(const f32x4*)(src);
    f32x4 a1 = *(const f32x4*)(src + 4);
    f32x4 a2 = *(const f32x4*)(src + 8);
    f32x4 a3 = *(const f32x4*)(src + 12);
    *(uint4v*)(Xb + (size_t)p * 16)     = cvt8(a0, a1);
    *(uint4v*)(Xb + (size_t)p * 16 + 8) = cvt8(a2, a3);
  }
}

// ---------------- fast pass (round-5 structure + in-kernel vcomp)
// MODE 0: uniform c -> partials of sum_i u  (2 i's packed into K=32)
// MODE 1: c = softmax_j(u.v) -> partials of sum_i c*u ; v = squash_J(S1)
//         [+ squash_J(S2) if S2 != null], computed per-thread from L2-hot S.
// Block: 256 thr = 4 waves = (2 b-tiles)x(2 j-halves); bhalf = blockIdx.x&1.
template<int MODE>
__global__ __launch_bounds__(256, 2)
void caps_pass_f(const u16* __restrict__ Wb,   // bf16 [NI][8192]
                 const u16* __restrict__ Xb,   // bf16 [NI][64][16]  (transposed)
                 const float* __restrict__ S1, // [64][512] (MODE 1)
                 const float* __restrict__ S2, // [64][512] or null (MODE 1 pass C)
                 float* __restrict__ partials, int CI)
{
  constexpr int WR = (MODE == 0) ? 2 : 1;
  __shared__ __align__(16) u16 sW[2][WR * 8192];
  __shared__ __align__(16) u16 sX[2][WR * 512];
  __shared__ float sSum[4][16];

  const int t = threadIdx.x, w = t >> 6, lane = t & 63;
  const int wtile = w & 1, jhalf = w >> 1, lq = lane >> 4, lb = lane & 15, q1 = lq & 1;
  const int bhalf = blockIdx.x & 1, iblk = blockIdx.x >> 1;
  const int bloc = wtile * 16 + lb, bg = bhalf * 32 + bloc;
  const size_t i0 = (size_t)iblk * (size_t)CI;
  const short8 zero8 = {0,0,0,0,0,0,0,0};
  const f32x4 zf4 = {0.f,0.f,0.f,0.f};

  f32x4 acc[16];
  #pragma unroll
  for (int tj = 0; tj < 16; ++tj) acc[tj] = zf4;

  // v packed bf16 (32 VGPR), computed from S buffers (validated in R8)
  unsigned int vpl[16], vph[16];
  if constexpr (MODE == 1){
    auto vcomp = [&](const float* S, bool addprev){
      const float* Srow = S + bg * 512 + lq * 4;   // this thread's 4 d-components
      f32x4 sq = zf4;
      #pragma unroll 8
      for (int j = 0; j < 32; ++j){
        f32x4 sv = *(const f32x4*)(Srow + j * 16);
        sq.x += sv.x * sv.x; sq.y += sv.y * sv.y;
        sq.z += sv.z * sv.z; sq.w += sv.w * sv.w;
      }
      f32x4 f;
      f.x = sq.x / ((1.f + sq.x) * sqrtf(sq.x + 1e-8f));
      f.y = sq.y / ((1.f + sq.y) * sqrtf(sq.y + 1e-8f));
      f.z = sq.z / ((1.f + sq.z) * sqrtf(sq.z + 1e-8f));
      f.w = sq.w / ((1.f + sq.w) * sqrtf(sq.w + 1e-8f));
      #pragma unroll
      for (int tj = 0; tj < 16; ++tj){
        f32x4 sv = *(const f32x4*)(Srow + (jhalf * 16 + tj) * 16);
        float v0 = sv.x * f.x, v1 = sv.y * f.y, v2 = sv.z * f.z, v3 = sv.w * f.w;
        if (addprev){
          v0 += bflo(vpl[tj]); v1 += bfhi(vpl[tj]);
          v2 += bflo(vph[tj]); v3 += bfhi(vph[tj]);
        }
        vpl[tj] = packbf2(v0, v1);
        vph[tj] = packbf2(v2, v3);
      }
    };
    vcomp(S1, false);
    if (S2) vcomp(S2, true);   // v12 = squash(S1) + squash(S2)
  }

  auto stage = [&](int nb, size_t irow){
    #pragma unroll
    for (int rr = 0; rr < WR; ++rr){
      const u16* src = Wb + (irow + rr) * 8192 + (size_t)(w * 4) * 512;
      u16* dst = &sW[nb][rr * 8192 + w * 4 * 512];
      #pragma unroll
      for (int r = 0; r < 4; ++r)
        gl_lds16(src + r * 512 + lane * 8, dst + r * 512);
    }
    if (w >= 4 - WR){
      int rr = w - (4 - WR);
      gl_lds16(Xb + ((irow + rr) * 64 + (size_t)bhalf * 32) * 16 + lane * 8,
               &sX[nb][rr * 512]);
    }
  };

  const int NSTEP = CI / WR;
  stage(0, i0);
  __syncthreads();

  for (int s = 0; s < NSTEP; ++s){
    const int buf = s & 1;
    if (s + 1 < NSTEP) stage(buf ^ 1, i0 + (size_t)(s + 1) * WR);  // async

    if constexpr (MODE == 0){
      // K=32 = (e of i0 | e of i1): quads 0,1 -> row 0; quads 2,3 -> row 1
      const int rsel = lq >> 1;
      short8 bfrag = *(const short8*)(&sX[buf][rsel * 512 + bloc * 16 + q1 * 8]);
      #pragma unroll
      for (int tj = 0; tj < 16; ++tj){
        int j = jhalf * 16 + tj;
        short8 afrag = *(const short8*)(&sW[buf][rsel * 8192 + j * 256 + lb * 16 + q1 * 8]);
        acc[tj] = __builtin_amdgcn_mfma_f32_16x16x32_bf16(afrag, bfrag, acc[tj], 0, 0, 0);
      }
    } else {
      short8 bl8 = *(const short8*)(&sX[buf][bloc * 16 + q1 * 8]);
      short8 bfrag = (lq < 2) ? bl8 : zero8;    // K upper half zero
      f32x4 ut[16];
      float e[16];
      // phase 1: u tiles (kept in regs) -> per-lane logits -> exps
      #pragma unroll
      for (int tj = 0; tj < 16; ++tj){
        int j = jhalf * 16 + tj;
        short8 al8 = *(const short8*)(&sW[buf][j * 256 + lb * 16 + q1 * 8]);
        short8 afrag = (lq < 2) ? al8 : zero8;
        ut[tj] = __builtin_amdgcn_mfma_f32_16x16x32_bf16(afrag, bfrag, zf4, 0, 0, 0);
        float p = ut[tj].x * bflo(vpl[tj]) + ut[tj].y * bfhi(vpl[tj])
                + ut[tj].z * bflo(vph[tj]) + ut[tj].w * bfhi(vph[tj]);
        p += __shfl_xor(p, 16, 64);
        p += __shfl_xor(p, 32, 64);   // every lane: full logit[j][its b]
        e[tj] = __expf(p);            // |logit| small -> fp32-safe w/o max-sub
      }
      // depth-4 tree sum of the 16 exps
      float s01 = e[0] + e[1],   s23 = e[2] + e[3];
      float s45 = e[4] + e[5],   s67 = e[6] + e[7];
      float s89 = e[8] + e[9],   sab = e[10] + e[11];
      float scd = e[12] + e[13], sef = e[14] + e[15];
      float ps = ((s01 + s23) + (s45 + s67)) + ((s89 + sab) + (scd + sef));
      // exchange partial denominator with the other j-half wave (same wtile)
      if (lane < 16) sSum[w][lane] = ps;
      __syncthreads();
      float inv = 1.0f / (ps + sSum[w ^ 2][lb]);
      // phase 2: accumulate c*u from registers
      #pragma unroll
      for (int tj = 0; tj < 16; ++tj){
        float c = e[tj] * inv;
        acc[tj].x += c * ut[tj].x;
        acc[tj].y += c * ut[tj].y;
        acc[tj].z += c * ut[tj].z;
        acc[tj].w += c * ut[tj].w;
      }
    }
    __syncthreads();
  }

  float* dst = partials + ((size_t)blockIdx.x * 4 + (size_t)w) * 4096 + (size_t)lane * 64;
  #pragma unroll
  for (int tj = 0; tj < 16; ++tj) *(f32x4*)(dst + tj * 4) = acc[tj];
}

// ---------------- reduce: sum 256 planes, un-permute -> S_buf[b][jd]
__global__ __launch_bounds__(128)
void caps_reduce(const float* __restrict__ partials, float* __restrict__ S_buf, float scale)
{
  const int T = blockIdx.x * 128 + threadIdx.x;   // 0..32767
  float s0 = 0.f, s1 = 0.f, s2 = 0.f, s3 = 0.f;
  #pragma unroll 4
  for (int bl = 0; bl < 256; bl += 4){
    s0 += partials[(size_t)(bl + 0) * 32768 + T];
    s1 += partials[(size_t)(bl + 1) * 32768 + T];
    s2 += partials[(size_t)(bl + 2) * 32768 + T];
    s3 += partials[(size_t)(bl + 3) * 32768 + T];
  }
  float s = ((s0 + s1) + (s2 + s3)) * scale;
  const int bhalf = T >> 14, w = (T >> 12) & 3, l = (T >> 6) & 63, k = T & 63;
  const int b  = bhalf * 32 + (w & 1) * 16 + (l & 15);
  const int jd = ((w >> 1) * 16 + (k >> 2)) * 16 + ((l >> 4) << 2) + (k & 3);
  S_buf[b * 512 + jd] = s;
}

// ---------------- final squash over D (axis=-1): fp32 output [B][J][D]
__global__ __launch_bounds__(256)
void caps_squash_d(const float* __restrict__ S, float* __restrict__ out)
{
  const int b = blockIdx.x, t = threadIdx.x;
  __shared__ float sq[32];
  if (t < 32) sq[t] = 0.f;
  __syncthreads();
  float s0 = S[b * 512 + t], s1 = S[b * 512 + 256 + t];
  atomicAdd(&sq[t >> 4], s0 * s0);
  atomicAdd(&sq[(t + 256) >> 4], s1 * s1);
  __syncthreads();
  float q0 = sq[t >> 4], q1 = sq[(t + 256) >> 4];
  out[b * 512 + t]       = s0 * q0 / ((1.f + q0) * sqrtf(q0 + 1e-8f));
  out[b * 512 + 256 + t] = s1 * q1 / ((1.f + q1) * sqrtf(q1 + 1e-8f));
}

// ======================= legacy fp32-input fallback (small ws) =======================
template<int MODE>
__global__ __launch_bounds__(256)
void caps_pass_legacy(const float* __restrict__ Wg, const float* __restrict__ Xg,
                      const float* __restrict__ vbuf, float* __restrict__ partials, int CI)
{
  __shared__ __align__(16) unsigned short sW[2][8192];
  __shared__ __align__(16) unsigned int   sXd[2][256];
  __shared__ float sLog[(MODE == 1) ? (32 * 33) : 4];
  const int t = threadIdx.x, w = t >> 6, lane = t & 63;
  const int wtile = w & 1, jhalf = w >> 1, lq = lane >> 4, lb = lane & 15, q1 = lq & 1;
  const int bhalf = blockIdx.x & 1, iblk = blockIdx.x >> 1;
  const int bloc = wtile * 16 + lb, bg = bhalf * 32 + bloc;
  const size_t i0 = (size_t)iblk * (size_t)CI;
  const short8 zero8 = {0,0,0,0,0,0,0,0};
  const f32x4 zf4 = {0.f,0.f,0.f,0.f};
  f32x4 acc[16];
  #pragma unroll
  for (int tj = 0; tj < 16; ++tj) acc[tj] = zf4;
  unsigned int vpl[16], vph[16];
  if constexpr (MODE == 1){
    #pragma unroll
    for (int tj = 0; tj < 16; ++tj){
      f32x4 v = *(const f32x4*)(&vbuf[bg * 512 + (jhalf * 16 + tj) * 16 + lq * 4]);
      vpl[tj] = packbf2(v.x, v.y); vph[tj] = packbf2(v.z, v.w);
    }
  }
  {
    const float* wsrc = Wg + i0 * 8192;
    #pragma unroll
    for (int r = 0; r < 4; ++r){
      int c = r * 256 + t;
      f32x4 a = *(const f32x4*)(&wsrc[c * 8]);
      f32x4 b = *(const f32x4*)(&wsrc[c * 8 + 4]);
      *(uint4v*)(&sW[0][c * 8]) = cvt8(a, b);
    }
    int bidx = bhalf * 32 + (t >> 3), e2 = t & 7;
    f32x2 xv = *(const f32x2*)(&Xg[((size_t)bidx * NI + i0) * 16 + e2 * 2]);
    sXd[0][t] = packbf2(xv.x, xv.y);
  }
  __syncthreads();
  for (int s = 0; s < CI; ++s){
    const int buf = s & 1;
    f32x4 wpa[4], wpb[4]; f32x2 xp;
    const bool more = (s + 1 < CI);
    if (more){
      const float* wsrc = Wg + (i0 + (size_t)(s + 1)) * 8192;
      #pragma unroll
      for (int r = 0; r < 4; ++r){
        int c = r * 256 + t;
        wpa[r] = *(const f32x4*)(&wsrc[c * 8]);
        wpb[r] = *(const f32x4*)(&wsrc[c * 8 + 4]);
      }
      int bidx = bhalf * 32 + (t >> 3), e2 = t & 7;
      xp = *(const f32x2*)(&Xg[((size_t)bidx * NI + i0 + s + 1) * 16 + e2 * 2]);
    }
    const unsigned short* xrow = (const unsigned short*)&sXd[buf][0];
    short8 bl8 = *(const short8*)(&xrow[bloc * 16 + q1 * 8]);
    short8 bfrag = (lq < 2) ? bl8 : zero8;
    if constexpr (MODE == 0){
      #pragma unroll
      for (int tj = 0; tj < 16; ++tj){
        int j = jhalf * 16 + tj;
        short8 al8 = *(const short8*)(&sW[buf][j * 256 + lb * 16 + q1 * 8]);
        short8 afrag = (lq < 2) ? al8 : zero8;
        acc[tj] = __builtin_amdgcn_mfma_f32_16x16x32_bf16(afrag, bfrag, acc[tj], 0, 0, 0);
      }
    } else {
      #pragma unroll
      for (int tj = 0; tj < 16; ++tj){
        int j = jhalf * 16 + tj;
        short8 al8 = *(const short8*)(&sW[buf][j * 256 + lb * 16 + q1 * 8]);
        short8 afrag = (lq < 2) ? al8 : zero8;
        f32x4 u = __builtin_amdgcn_mfma_f32_16x16x32_bf16(afrag, bfrag, zf4, 0, 0, 0);
        float p = u.x * bflo(vpl[tj]) + u.y * bfhi(vpl[tj])
                + u.z * bflo(vph[tj]) + u.w * bfhi(vph[tj]);
        p += __shfl_xor(p, 16, 64);
        p += __shfl_xor(p, 32, 64);
        if (lane < 16) sLog[bloc * 33 + j] = p;
      }
      __syncthreads();
      const float* logrow = &sLog[bloc * 33];
      float ssum = 0.f;
      #pragma unroll
      for (int jj = 0; jj < 32; ++jj) ssum += __expf(logrow[jj]);
      float inv = 1.0f / ssum;
      #pragma unroll
      for (int tj = 0; tj < 16; ++tj){
        int j = jhalf * 16 + tj;
        short8 al8 = *(const short8*)(&sW[buf][j * 256 + lb * 16 + q1 * 8]);
        short8 afrag = (lq < 2) ? al8 : zero8;
        f32x4 u = __builtin_amdgcn_mfma_f32_16x16x32_bf16(afrag, bfrag, zf4, 0, 0, 0);
        float c = __expf(logrow[j]) * inv;
        acc[tj].x += c * u.x; acc[tj].y += c * u.y;
        acc[tj].z += c * u.z; acc[tj].w += c * u.w;
      }
    }
    if (more){
      const int nb = buf ^ 1;
      #pragma unroll
      for (int r = 0; r < 4; ++r){
        int c = r * 256 + t;
        *(uint4v*)(&sW[nb][c * 8]) = cvt8(wpa[r], wpb[r]);
      }
      sXd[nb][t] = packbf2(xp.x, xp.y);
    }
    __syncthreads();
  }
  float* dst = partials + ((size_t)blockIdx.x * 4 + (size_t)w) * 4096 + (size_t)lane * 64;
  #pragma unroll
  for (int tj = 0; tj < 16; ++tj) *(f32x4*)(dst + tj * 4) = acc[tj];
}

template<int NBLK>
__global__ __launch_bounds__(128)
void caps_reduce_legacy(const float* __restrict__ partials, float* __restrict__ S_buf, float scale)
{
  const int T = blockIdx.x * 128 + threadIdx.x;
  float s0 = 0.f, s1 = 0.f, s2 = 0.f, s3 = 0.f;
  #pragma unroll 4
  for (int bl = 0; bl < NBLK; bl += 4){
    s0 += partials[(size_t)(bl + 0) * 32768 + T];
    s1 += partials[(size_t)(bl + 1) * 32768 + T];
    s2 += partials[(size_t)(bl + 2) * 32768 + T];
    s3 += partials[(size_t)(bl + 3) * 32768 + T];
  }
  float s = ((s0 + s1) + (s2 + s3)) * scale;
  const int bhalf = T >> 14, w = (T >> 12) & 3, l = (T >> 6) & 63, k = T & 63;
  const int b  = bhalf * 32 + (w & 1) * 16 + (l & 15);
  const int jd = ((w >> 1) * 16 + (k >> 2)) * 16 + ((l >> 4) << 2) + (k & 3);
  S_buf[b * 512 + jd] = s;
}

__global__ __launch_bounds__(256)
void caps_squash_j(const float* __restrict__ S, const float* __restrict__ vprev,
                   float* __restrict__ vout)
{
  const int b = blockIdx.x, t = threadIdx.x;
  __shared__ float sq[16];
  if (t < 16) sq[t] = 0.f;
  __syncthreads();
  float s0 = S[b * 512 + t], s1 = S[b * 512 + 256 + t];
  atomicAdd(&sq[t & 15], s0 * s0 + s1 * s1);
  __syncthreads();
  float q = sq[t & 15];
  float f = q / ((1.f + q) * sqrtf(q + 1e-8f));
  float v0 = s0 * f, v1 = s1 * f;
  if (vprev){ v0 += vprev[b * 512 + t]; v1 += vprev[b * 512 + 256 + t]; }
  vout[b * 512 + t] = v0;
  vout[b * 512 + 256 + t] = v1;
}

extern "C" void kernel_launch(void* const* d_in, const int* in_sizes, int n_in,
                              void* d_out, int out_size, void* d_ws, size_t ws_size,
                              hipStream_t stream)
{
  const float* X = (const float*)d_in[0];  // fp32 [64][2048][16]
  const float* W = (const float*)d_in[1];  // fp32 [2048][32][16][16]
  float* wsf = (float*)d_ws;
  float* outp = (float*)d_out;

  const size_t WB_ELE = (size_t)NI * 8192, XB_ELE = (size_t)NI * 64 * 16;
  const size_t FP = (size_t)256 * 32768;
  const size_t need_full = (FP + 3 * 32768) * 4 + (WB_ELE + XB_ELE) * 2;

  if (ws_size >= need_full){
    float* partials = wsf;
    float* S1 = wsf + FP;
    float* S2 = S1 + 32768;
    float* S3 = S2 + 32768;
    u16* Wb = (u16*)(S3 + 32768);
    u16* Xb = Wb + WB_ELE;

    caps_prep<<<dim3(8704), dim3(256), 0, stream>>>(W, X, Wb, Xb);

    // pass A (uniform c, WR=2) -> S1
    caps_pass_f<0><<<dim3(512), dim3(256), 0, stream>>>(Wb, Xb, nullptr, nullptr, partials, 8);
    caps_reduce<<<dim3(256), dim3(128), 0, stream>>>(partials, S1, 1.0f / 32.0f);
    // pass B: v1 = squash_J(S1) in-kernel -> S2
    caps_pass_f<1><<<dim3(512), dim3(256), 0, stream>>>(Wb, Xb, S1, nullptr, partials, 8);
    caps_reduce<<<dim3(256), dim3(128), 0, stream>>>(partials, S2, 1.0f);
    // pass C: v12 = squash_J(S1) + squash_J(S2) in-kernel -> S3
    caps_pass_f<1><<<dim3(512), dim3(256), 0, stream>>>(Wb, Xb, S1, S2, partials, 8);
    caps_reduce<<<dim3(256), dim3(128), 0, stream>>>(partials, S3, 1.0f);
    caps_squash_d<<<dim3(64), dim3(256), 0, stream>>>(S3, outp);
  } else {
    // legacy fp32-input ladder for tiny ws
    int nbi = 256;
    auto need = [](int nb){ return ((size_t)nb * 32768 + 3 * 32768) * 4; };
    if (ws_size < need(256)){
      if      (ws_size >= need(64)) nbi = 64;
      else if (ws_size >= need(16)) nbi = 16;
      else                          nbi = 4;
    }
    const int CI = NI / nbi;
    float* partials = wsf;
    float* sbuf = wsf + (size_t)nbi * 32768;
    float* v1   = sbuf + 32768;
    float* v12  = v1 + 32768;
    auto reduce = [&](float scale){
      if      (nbi == 256) caps_reduce_legacy<256><<<dim3(256), dim3(128), 0, stream>>>(partials, sbuf, scale);
      else if (nbi ==  64) caps_reduce_legacy< 64><<<dim3(256), dim3(128), 0, stream>>>(partials, sbuf, scale);
      else if (nbi ==  16) caps_reduce_legacy< 16><<<dim3(256), dim3(128), 0, stream>>>(partials, sbuf, scale);
      else                 caps_reduce_legacy<  4><<<dim3(256), dim3(128), 0, stream>>>(partials, sbuf, scale);
    };
    caps_pass_legacy<0><<<dim3(2 * nbi), dim3(256), 0, stream>>>(W, X, nullptr, partials, CI);
    reduce(1.0f / 32.0f);
    caps_squash_j<<<dim3(64), dim3(256), 0, stream>>>(sbuf, nullptr, v1);
    caps_pass_legacy<1><<<dim3(2 * nbi), dim3(256), 0, stream>>>(W, X, v1, partials, CI);
    reduce(1.0f);
    caps_squash_j<<<dim3(64), dim3(256), 0, stream>>>(sbuf, v1, v12);
    caps_pass_legacy<1><<<dim3(2 * nbi), dim3(256), 0, stream>>>(W, X, v12, partials, CI);
    reduce(1.0f);
    caps_squash_d<<<dim3(64), dim3(256), 0, stream>>>(sbuf, outp);
  }
}